// Round 4
// baseline (136.585 us; speedup 1.0000x reference)
//
#include <hip/hip_runtime.h>

// Cubic B-spline interpolation (SplineInter), 2D, m=1024x1024, PAD=2.
// Grid: coeffs (1028 x 1028) float32, flat-clamped gather per reference.
//
// R1: row-vectorized gathers (4x dwordx4/point): 111 -> 48 us.
// R2: 2 pts/thread MLP probe: no change -> gather-throughput bound, not latency.
// R3: count-sort points into 64x64 tiles, eval from LDS-staged 68x68 patch.
//     Moves 16 gathers/point off the L1/L2 fragmented path onto the DS pipe.

#define I1 1028
#define TOTAL (1028 * 1028)
#define NPTS_TILE 64            // grid cells per tile side
#define NTILE_SIDE 16           // 1024/64
#define NTILES 256
#define PATCH 68                // 64 + 4 halo/stencil reach
#define PATCH_STRIDE 69         // +1 pad (odd) for bank conflicts
#define BPT 4                   // eval blocks per tile
#define SORT_BLOCKS 256

typedef float f4u __attribute__((ext_vector_type(4), aligned(4)));

__device__ __forceinline__ void basis4(float t, float w[4]) {
    float a = 1.0f - t;
    w[0] = a * a * a;                                // j=-1: (1-t)^3
    w[1] = (3.0f * t - 6.0f) * (t * t) + 4.0f;       // j=0
    float xi = t - 1.0f;
    w[2] = -(3.0f * xi + 6.0f) * (xi * xi) + 4.0f;   // j=1
    w[3] = t * t * t;                                // j=2
}

// P0/P1 from the point, identical math everywhere (deterministic binning).
__device__ __forceinline__ void point_cell(float2 xy, int& P0, int& P1,
                                           float& t0, float& t1, bool& valid) {
    float xn0 = xy.x * 1024.0f - 0.5f;
    float xn1 = xy.y * 1024.0f - 0.5f;
    valid = (xn0 > -2.0f) && (xn0 < 1024.0f) &&
            (xn1 > -2.0f) && (xn1 < 1024.0f);
    float P0f = floorf(xn0);
    float P1f = floorf(xn1);
    P0 = (int)P0f;
    P1 = (int)P1f;
    t0 = xn0 - P0f;
    t1 = xn1 - P1f;
}

__device__ __forceinline__ int tile_of(int P0, int P1) {
    int ty = min(max(P0, 0), 1023) >> 6;
    int tx = min(max(P1, 0), 1023) >> 6;
    return ty * NTILE_SIDE + tx;
}

// Exact reference semantics: flat-clamped scalar gather.
__device__ __forceinline__ float eval_slow(const float* __restrict__ coeffs,
                                           int base, const float w0[4],
                                           const float w1[4]) {
    float acc = 0.0f;
#pragma unroll
    for (int j = 0; j < 4; ++j) {
        int r = base + (j - 1) * I1 - 1;
        float s = 0.0f;
#pragma unroll
        for (int k = 0; k < 4; ++k) {
            int idx = min(max(r + k, 0), TOTAL - 1);
            s = fmaf(coeffs[idx], w1[k], s);
        }
        acc = fmaf(s, w0[j], acc);
    }
    return acc;
}

// ---------------- sort pipeline ----------------

__global__ __launch_bounds__(256) void hist_kernel(
    const float2* __restrict__ x2, int* __restrict__ hist, int n)
{
    __shared__ int h[NTILES];
    h[threadIdx.x] = 0;
    __syncthreads();
    int stride = gridDim.x * blockDim.x;
    for (int p = blockIdx.x * blockDim.x + threadIdx.x; p < n; p += stride) {
        int P0, P1; float t0, t1; bool valid;
        point_cell(x2[p], P0, P1, t0, t1, valid);
        atomicAdd(&h[tile_of(P0, P1)], 1);
    }
    __syncthreads();
    atomicAdd(&hist[threadIdx.x], h[threadIdx.x]);
}

__global__ __launch_bounds__(256) void scan_kernel(
    const int* __restrict__ hist, int* __restrict__ offsets,
    int* __restrict__ cursor, int n)
{
    __shared__ int h[NTILES];
    int t = threadIdx.x;
    h[t] = hist[t];
    __syncthreads();
    if (t == 0) {
        int acc = 0;
        for (int i = 0; i < NTILES; ++i) { int c = h[i]; h[i] = acc; acc += c; }
    }
    __syncthreads();
    offsets[t] = h[t];
    cursor[t] = h[t];
    if (t == 0) offsets[NTILES] = n;
}

__global__ __launch_bounds__(256) void scatter_kernel(
    const float2* __restrict__ x2, int* __restrict__ cursor,
    float2* __restrict__ sxy, int* __restrict__ sidx, int n)
{
    __shared__ int h[NTILES];
    __shared__ int base[NTILES];
    int t = threadIdx.x;
    int chunk = (n + gridDim.x - 1) / gridDim.x;
    int lo = blockIdx.x * chunk;
    int hi = min(n, lo + chunk);

    h[t] = 0;
    __syncthreads();
    for (int p = lo + t; p < hi; p += blockDim.x) {
        int P0, P1; float t0, t1; bool valid;
        point_cell(x2[p], P0, P1, t0, t1, valid);
        atomicAdd(&h[tile_of(P0, P1)], 1);
    }
    __syncthreads();
    base[t] = atomicAdd(&cursor[t], h[t]);
    h[t] = 0;
    __syncthreads();
    for (int p = lo + t; p < hi; p += blockDim.x) {
        float2 xy = x2[p];
        int P0, P1; float t0, t1; bool valid;
        point_cell(xy, P0, P1, t0, t1, valid);
        int tile = tile_of(P0, P1);
        int r = atomicAdd(&h[tile], 1);
        int pos = base[tile] + r;
        sxy[pos] = xy;
        sidx[pos] = p;
    }
}

// ---------------- eval ----------------

__global__ __launch_bounds__(256) void eval_kernel(
    const float2* __restrict__ sxy, const int* __restrict__ sidx,
    const int* __restrict__ offsets, const float* __restrict__ coeffs,
    float* __restrict__ out)
{
    __shared__ float s_tile[PATCH * PATCH_STRIDE];

    int tile = blockIdx.x / BPT;
    int chunk = blockIdx.x % BPT;
    int ty = tile / NTILE_SIDE;
    int tx = tile % NTILE_SIDE;
    int row0 = ty * NPTS_TILE;   // padded-grid row of patch origin
    int col0 = tx * NPTS_TILE;

    // Stage 68x68 patch (always fully in-bounds: row0+67 <= 1027).
    for (int i = threadIdx.x; i < PATCH * PATCH; i += blockDim.x) {
        int r = i / PATCH;
        int c = i - r * PATCH;
        s_tile[r * PATCH_STRIDE + c] = coeffs[(row0 + r) * I1 + (col0 + c)];
    }
    __syncthreads();

    int seg_lo = offsets[tile];
    int seg_hi = offsets[tile + 1];

    for (int p = seg_lo + chunk * 256 + (int)threadIdx.x; p < seg_hi;
         p += BPT * 256) {
        float2 xy = sxy[p];
        int P0, P1; float t0, t1; bool valid;
        point_cell(xy, P0, P1, t0, t1, valid);

        float w0[4], w1[4];
        basis4(t0, w0);
        basis4(t1, w1);

        int lr = P0 + 1 - row0;   // stencil top row within patch
        int lc = P1 + 1 - col0;   // stencil left col within patch

        float acc;
        if (lr >= 0 && lr <= 64 && lc >= 0 && lc <= 64) {
            acc = 0.0f;
#pragma unroll
            for (int j = 0; j < 4; ++j) {
                const float* row = &s_tile[(lr + j) * PATCH_STRIDE + lc];
                float s = fmaf(row[0], w1[0],
                          fmaf(row[1], w1[1],
                          fmaf(row[2], w1[2],
                               row[3] * w1[3])));
                acc = fmaf(s, w0[j], acc);
            }
        } else {
            int base = I1 * (2 + P0) + (2 + P1);
            acc = eval_slow(coeffs, base, w0, w1);
        }
        out[sidx[p]] = valid ? acc : 0.0f;
    }
}

// ---------------- fallback (small ws): R2 kernel ----------------

__global__ __launch_bounds__(256) void spline_direct_kernel(
    const float* __restrict__ x, const float* __restrict__ coeffs,
    float* __restrict__ out, int n)
{
    int i = blockIdx.x * blockDim.x + threadIdx.x;
    if (i >= n) return;
    float2 xy = reinterpret_cast<const float2*>(x)[i];
    int P0, P1; float t0, t1; bool valid;
    point_cell(xy, P0, P1, t0, t1, valid);
    float w0[4], w1[4];
    basis4(t0, w0);
    basis4(t1, w1);
    int base = I1 * (2 + P0) + (2 + P1);
    bool interior = (base - I1 - 1 >= 0) && (base + 2 * I1 + 2 <= TOTAL - 1);
    float acc = 0.0f;
    if (interior) {
#pragma unroll
        for (int j = 0; j < 4; ++j) {
            f4u v = *reinterpret_cast<const f4u*>(coeffs + base + (j - 1) * I1 - 1);
            float s = fmaf(v.x, w1[0], fmaf(v.y, w1[1],
                      fmaf(v.z, w1[2], v.w * w1[3])));
            acc = fmaf(s, w0[j], acc);
        }
    } else {
        acc = eval_slow(coeffs, base, w0, w1);
    }
    out[i] = valid ? acc : 0.0f;
}

extern "C" void kernel_launch(void* const* d_in, const int* in_sizes, int n_in,
                              void* d_out, int out_size, void* d_ws, size_t ws_size,
                              hipStream_t stream) {
    const float* x = (const float*)d_in[0];       // [N,2]
    const float* coeffs = (const float*)d_in[1];  // [1028*1028]
    float* out = (float*)d_out;                   // [N]
    int n = in_sizes[0] / 2;                      // 2,097,152 points

    size_t need = 4096 + (size_t)n * 12;
    if (ws_size < need) {
        int block = 256;
        int grid = (n + block - 1) / block;
        spline_direct_kernel<<<grid, block, 0, stream>>>(x, coeffs, out, n);
        return;
    }

    char* ws = (char*)d_ws;
    int* hist    = (int*)(ws);            // 256 ints
    int* offsets = (int*)(ws + 1024);     // 257 ints
    int* cursor  = (int*)(ws + 2560);     // 256 ints
    float2* sxy  = (float2*)(ws + 4096);  // n float2
    int* sidx    = (int*)(ws + 4096 + (size_t)n * 8);  // n ints

    const float2* x2 = (const float2*)x;

    hipMemsetAsync(d_ws, 0, 4096, stream);
    hist_kernel<<<SORT_BLOCKS, 256, 0, stream>>>(x2, hist, n);
    scan_kernel<<<1, 256, 0, stream>>>(hist, offsets, cursor, n);
    scatter_kernel<<<SORT_BLOCKS, 256, 0, stream>>>(x2, cursor, sxy, sidx, n);
    eval_kernel<<<NTILES * BPT, 256, 0, stream>>>(sxy, sidx, offsets, coeffs, out);
}

// Round 5
// 115.238 us; speedup vs baseline: 1.1852x; 1.1852x over previous
//
#include <hip/hip_runtime.h>

// Cubic B-spline interpolation (SplineInter), 2D, m=1024x1024, PAD=2.
// Grid: coeffs (1028 x 1028) float32, flat-clamped gather per reference.
//
// R1: row-vectorized gathers (4x dwordx4/point): 111 -> 48 us.
// R2: 2 pts/thread MLP probe: no change -> gather-throughput bound, not latency.
// R3: hist/scan/scatter/eval sort pipeline: ~75 us GPU (scattered-store cost
//     ~= scattered-gather cost; 6M scattered requests + 2 extra passes).
// R4: minimum-scattered-request pipeline: fixed-capacity segments (no hist/
//     scan), scatter packs (x,y,idx) into ONE 16B store/point, eval from LDS
//     patch with ONE 4B out store/point. 4M scattered requests total.

#define I1 1028
#define TOTAL (1028 * 1028)
#define NPTS_TILE 64            // grid cells per tile side
#define NTILE_SIDE 16           // 1024/64
#define NTILES 256
#define PATCH 68                // 64 + 4 halo/stencil reach
#define PATCH_STRIDE 69         // +1 pad (odd) vs 32 banks
#define BPT 4                   // eval blocks per tile
#define CAP 10240               // slots per tile (mean 8192, sd 90 -> +22 sd)
#define SORT_BLOCKS 256

typedef float f4u __attribute__((ext_vector_type(4), aligned(4)));

__device__ __forceinline__ void basis4(float t, float w[4]) {
    float a = 1.0f - t;
    w[0] = a * a * a;                                // j=-1: (1-t)^3
    w[1] = (3.0f * t - 6.0f) * (t * t) + 4.0f;       // j=0
    float xi = t - 1.0f;
    w[2] = -(3.0f * xi + 6.0f) * (xi * xi) + 4.0f;   // j=1
    w[3] = t * t * t;                                // j=2
}

__device__ __forceinline__ void point_cell(float2 xy, int& P0, int& P1,
                                           float& t0, float& t1, bool& valid) {
    float xn0 = xy.x * 1024.0f - 0.5f;
    float xn1 = xy.y * 1024.0f - 0.5f;
    valid = (xn0 > -2.0f) && (xn0 < 1024.0f) &&
            (xn1 > -2.0f) && (xn1 < 1024.0f);
    float P0f = floorf(xn0);
    float P1f = floorf(xn1);
    P0 = (int)P0f;
    P1 = (int)P1f;
    t0 = xn0 - P0f;
    t1 = xn1 - P1f;
}

__device__ __forceinline__ int tile_of(int P0, int P1) {
    int ty = min(max(P0, 0), 1023) >> 6;
    int tx = min(max(P1, 0), 1023) >> 6;
    return ty * NTILE_SIDE + tx;
}

// Exact reference semantics: flat-clamped scalar gather (always correct).
__device__ __forceinline__ float eval_slow(const float* __restrict__ coeffs,
                                           int base, const float w0[4],
                                           const float w1[4]) {
    float acc = 0.0f;
#pragma unroll
    for (int j = 0; j < 4; ++j) {
        int r = base + (j - 1) * I1 - 1;
        float s = 0.0f;
#pragma unroll
        for (int k = 0; k < 4; ++k) {
            int idx = min(max(r + k, 0), TOTAL - 1);
            s = fmaf(coeffs[idx], w1[k], s);
        }
        acc = fmaf(s, w0[j], acc);
    }
    return acc;
}

// ---------------- scatter (single pass over x) ----------------

__global__ __launch_bounds__(256) void scatter_kernel(
    const float2* __restrict__ x2, int* __restrict__ gcount,
    float4* __restrict__ spts, const float* __restrict__ coeffs,
    float* __restrict__ out, int n)
{
    __shared__ int h[NTILES];
    __shared__ int base[NTILES];
    int t = threadIdx.x;
    int chunk = (n + gridDim.x - 1) / gridDim.x;
    int lo = blockIdx.x * chunk;
    int hi = min(n, lo + chunk);

    h[t] = 0;
    __syncthreads();
    for (int p = lo + t; p < hi; p += blockDim.x) {
        int P0, P1; float t0, t1; bool valid;
        point_cell(x2[p], P0, P1, t0, t1, valid);
        atomicAdd(&h[tile_of(P0, P1)], 1);
    }
    __syncthreads();
    int cnt = h[t];
    base[t] = cnt > 0 ? atomicAdd(&gcount[t], cnt) : 0;
    h[t] = 0;
    __syncthreads();
    for (int p = lo + t; p < hi; p += blockDim.x) {
        float2 xy = x2[p];
        int P0, P1; float t0, t1; bool valid;
        point_cell(xy, P0, P1, t0, t1, valid);
        int tile = tile_of(P0, P1);
        int r = atomicAdd(&h[tile], 1);
        int slot = base[tile] + r;
        if (slot < CAP) {
            float4 v;
            v.x = xy.x; v.y = xy.y; v.z = __int_as_float(p); v.w = 0.0f;
            spts[(size_t)tile * CAP + slot] = v;   // one 16B-aligned store
        } else {
            // Overflow (statistically never): exact direct eval.
            float w0[4], w1[4];
            basis4(t0, w0);
            basis4(t1, w1);
            int b = I1 * (2 + P0) + (2 + P1);
            out[p] = valid ? eval_slow(coeffs, b, w0, w1) : 0.0f;
        }
    }
}

// ---------------- eval from LDS patch ----------------

__global__ __launch_bounds__(256) void eval_kernel(
    const float4* __restrict__ spts, const int* __restrict__ gcount,
    const float* __restrict__ coeffs, float* __restrict__ out)
{
    __shared__ float s_tile[PATCH * PATCH_STRIDE];

    int tile = blockIdx.x >> 2;          // BPT = 4
    int chunk = blockIdx.x & (BPT - 1);
    int ty = tile >> 4;
    int tx = tile & (NTILE_SIDE - 1);
    int row0 = ty * NPTS_TILE;
    int col0 = tx * NPTS_TILE;

    // Stage 68x68 patch (always fully in-bounds: row0+67 <= 1027).
    for (int i = threadIdx.x; i < PATCH * PATCH; i += 256) {
        int r = i / PATCH;
        int c = i - r * PATCH;
        s_tile[r * PATCH_STRIDE + c] = coeffs[(row0 + r) * I1 + (col0 + c)];
    }
    __syncthreads();

    int count = min(gcount[tile], CAP);
    const float4* seg = spts + (size_t)tile * CAP;

    for (int q = chunk * 256 + (int)threadIdx.x; q < count; q += BPT * 256) {
        float4 v = seg[q];
        float2 xy = make_float2(v.x, v.y);
        int p = __float_as_int(v.z);

        int P0, P1; float t0, t1; bool valid;
        point_cell(xy, P0, P1, t0, t1, valid);

        float w0[4], w1[4];
        basis4(t0, w0);
        basis4(t1, w1);

        int lr = P0 + 1 - row0;   // stencil top row within patch
        int lc = P1 + 1 - col0;   // stencil left col within patch

        float acc;
        if (lr >= 0 && lr <= NPTS_TILE && lc >= 0 && lc <= NPTS_TILE) {
            acc = 0.0f;
#pragma unroll
            for (int j = 0; j < 4; ++j) {
                const float* row = &s_tile[(lr + j) * PATCH_STRIDE + lc];
                float s = fmaf(row[0], w1[0],
                          fmaf(row[1], w1[1],
                          fmaf(row[2], w1[2],
                               row[3] * w1[3])));
                acc = fmaf(s, w0[j], acc);
            }
        } else {
            int b = I1 * (2 + P0) + (2 + P1);
            acc = eval_slow(coeffs, b, w0, w1);
        }
        out[p] = valid ? acc : 0.0f;     // one 4B scattered store
    }
}

// ---------------- fallback (small ws): R2 direct kernel ----------------

__global__ __launch_bounds__(256) void spline_direct_kernel(
    const float* __restrict__ x, const float* __restrict__ coeffs,
    float* __restrict__ out, int n)
{
    int i = blockIdx.x * blockDim.x + threadIdx.x;
    if (i >= n) return;
    float2 xy = reinterpret_cast<const float2*>(x)[i];
    int P0, P1; float t0, t1; bool valid;
    point_cell(xy, P0, P1, t0, t1, valid);
    float w0[4], w1[4];
    basis4(t0, w0);
    basis4(t1, w1);
    int base = I1 * (2 + P0) + (2 + P1);
    bool interior = (base - I1 - 1 >= 0) && (base + 2 * I1 + 2 <= TOTAL - 1);
    float acc = 0.0f;
    if (interior) {
#pragma unroll
        for (int j = 0; j < 4; ++j) {
            f4u v = *reinterpret_cast<const f4u*>(coeffs + base + (j - 1) * I1 - 1);
            float s = fmaf(v.x, w1[0], fmaf(v.y, w1[1],
                      fmaf(v.z, w1[2], v.w * w1[3])));
            acc = fmaf(s, w0[j], acc);
        }
    } else {
        acc = eval_slow(coeffs, base, w0, w1);
    }
    out[i] = valid ? acc : 0.0f;
}

extern "C" void kernel_launch(void* const* d_in, const int* in_sizes, int n_in,
                              void* d_out, int out_size, void* d_ws, size_t ws_size,
                              hipStream_t stream) {
    const float* x = (const float*)d_in[0];       // [N,2]
    const float* coeffs = (const float*)d_in[1];  // [1028*1028]
    float* out = (float*)d_out;                   // [N]
    int n = in_sizes[0] / 2;                      // 2,097,152 points

    size_t need = 1024 + (size_t)NTILES * CAP * 16;
    if (ws_size < need) {
        int block = 256;
        int grid = (n + block - 1) / block;
        spline_direct_kernel<<<grid, block, 0, stream>>>(x, coeffs, out, n);
        return;
    }

    char* ws = (char*)d_ws;
    int* gcount  = (int*)ws;                 // 256 ints
    float4* spts = (float4*)(ws + 1024);     // NTILES * CAP float4

    const float2* x2 = (const float2*)x;

    hipMemsetAsync(gcount, 0, NTILES * sizeof(int), stream);
    scatter_kernel<<<SORT_BLOCKS, 256, 0, stream>>>(x2, gcount, spts, coeffs, out, n);
    eval_kernel<<<NTILES * BPT, 256, 0, stream>>>(spts, gcount, coeffs, out);
}